// Round 2
// baseline (1323.935 us; speedup 1.0000x reference)
//
#include <hip/hip_runtime.h>
#include <math.h>

#define NSPA 32768           // 32*32*32 spatial positions = L
#define EPS 1e-5f

// ---- stats arena offsets (floats, within d_ws[0..65535]) ----
#define ST_MEAN   0      // 192
#define ST_RSTD   192    // 192
#define ST_GM     384    // 192
#define ST_GRSTD  576    // 192
#define ST_X2SUM  768    // 192
#define ST_XH     1024   // 192*32
#define ST_XW     7168   // 192*32
#define ST_XD     13312  // 192*32
#define ST_GATE   19456  // 16*12*96 = 18432
#define ST_MEAN2  38400  // 192
#define ST_RSTD2  38592  // 192

__device__ __forceinline__ float sigmoidf_(float x){ return 1.f/(1.f+expf(-x)); }
__device__ __forceinline__ float siluf_(float x){ return x/(1.f+expf(-x)); }
__device__ __forceinline__ float geluf_(float x){ return 0.5f*x*(1.f+erff(x*0.70710678118654752f)); }
__device__ __forceinline__ float softplusf_(float x){ return fmaxf(x,0.f) + log1pf(expf(-fabsf(x))); }

// ============ K1: per-(b,c) instance-norm stats + SPPE pooled means ============
// grid 192, block 1024
__global__ void k_stats(const float* __restrict__ x, float* __restrict__ st) {
  int bc = blockIdx.x;
  int t = threadIdx.x;
  __shared__ float xh_s[32], xw_s[32], xd_s[32], red[16], red2[16];
  if (t < 32) { xh_s[t]=0.f; xw_s[t]=0.f; xd_s[t]=0.f; }
  __syncthreads();
  const float* px = x + (size_t)bc*NSPA;
  float s=0.f, s2=0.f;
  for (int it=0; it<32; ++it) {
    float v = px[it*1024 + t];
    s += v; s2 += v*v;
    float wv = v;
    #pragma unroll
    for (int m=32;m>=1;m>>=1) wv += __shfl_xor(wv,m);
    if ((t&63)==0) atomicAdd(&xh_s[it], wv);
  }
  atomicAdd(&xw_s[(t>>5)&31], s);
  atomicAdd(&xd_s[t&31], s);
  float rs=s, rs2=s2;
  #pragma unroll
  for (int m=32;m>=1;m>>=1){ rs += __shfl_xor(rs,m); rs2 += __shfl_xor(rs2,m); }
  if ((t&63)==0){ red[t>>6]=rs; red2[t>>6]=rs2; }
  __syncthreads();
  if (t==0){
    float S=0.f,S2=0.f;
    for (int w=0;w<16;w++){ S+=red[w]; S2+=red2[w]; }
    float mn = S/(float)NSPA;
    float var = S2/(float)NSPA - mn*mn;
    st[ST_MEAN+bc] = mn;
    st[ST_RSTD+bc] = rsqrtf(var+EPS);
  }
  if (t<32){
    st[ST_XH + bc*32 + t] = xh_s[t]*(1.f/1024.f);
    st[ST_XW + bc*32 + t] = xw_s[t]*(1.f/1024.f);
    st[ST_XD + bc*32 + t] = xd_s[t]*(1.f/1024.f);
  }
}

// ============ K2: SPPE 1x1 conv on pooled vectors -> sigmoid gates ============
// grid 16, block 128.  gates layout [bg][co][pos], pos<96
__global__ void k_gates(const float* __restrict__ c1w, const float* __restrict__ c1b,
                        float* __restrict__ st) {
  int bg = blockIdx.x; int b = bg>>3; int g = bg&7;
  for (int i = threadIdx.x; i < 12*96; i += 128) {
    int co = i/96, pos = i%96;
    float acc = c1b[co];
    for (int cg=0; cg<12; ++cg) {
      int bc = b*96 + g*12 + cg;
      float hv;
      if (pos < 32)      hv = st[ST_XH + bc*32 + pos];
      else if (pos < 64) hv = st[ST_XW + bc*32 + pos-32];
      else               hv = st[ST_XD + bc*32 + pos-64];
      acc += c1w[co*12+cg]*hv;
    }
    st[ST_GATE + bg*1152 + i] = sigmoidf_(acc);
  }
}

// ============ K3: gated = gx*gh*gw*gd, + group-norm stats ============
// grid 192, block 1024
__global__ void k_gated(const float* __restrict__ x, float* __restrict__ gated,
                        float* __restrict__ st) {
  int bc = blockIdx.x; int bg = bc/12; int cg = bc%12;
  int t = threadIdx.x;
  const float* gate = st + ST_GATE + bg*1152 + cg*96;
  float gw = gate[32 + (t>>5)];
  float gd = gate[64 + (t&31)];
  const float* px = x + (size_t)bc*NSPA;
  float* pg = gated + (size_t)bc*NSPA;
  __shared__ float red[16], red2[16];
  float s=0.f, s2=0.f;
  for (int it=0; it<32; ++it) {
    float gh = gate[it];
    float v = px[it*1024+t]*gh*gw*gd;
    pg[it*1024+t] = v;
    s += v; s2 += v*v;
  }
  #pragma unroll
  for (int m=32;m>=1;m>>=1){ s += __shfl_xor(s,m); s2 += __shfl_xor(s2,m); }
  if ((t&63)==0){ red[t>>6]=s; red2[t>>6]=s2; }
  __syncthreads();
  if (t==0){
    float S=0.f,S2=0.f;
    for (int w=0;w<16;w++){ S+=red[w]; S2+=red2[w]; }
    float mn = S/(float)NSPA;
    float var = S2/(float)NSPA - mn*mn;
    st[ST_GM+bc] = mn;
    st[ST_GRSTD+bc] = rsqrtf(var+EPS);
  }
}

// ============ K4: grouped 3x3x3 conv (x2) + per-channel spatial sums ============
// grid (128, 16), block 256
__global__ void k_conv3(const float* __restrict__ x, const float* __restrict__ c3w,
                        const float* __restrict__ c3b, float* __restrict__ x2,
                        float* __restrict__ st) {
  int bg = blockIdx.y;
  int l = blockIdx.x*256 + threadIdx.x;
  int h = l>>10, w = (l>>5)&31, d = l&31;
  __shared__ float sw[3888];
  __shared__ float sb[12], ssum[12];
  for (int i=threadIdx.x;i<3888;i+=256) sw[i]=c3w[i];
  if (threadIdx.x<12){ sb[threadIdx.x]=c3b[threadIdx.x]; ssum[threadIdx.x]=0.f; }
  __syncthreads();
  float acc[12];
  #pragma unroll
  for (int co=0;co<12;co++) acc[co]=0.f;
  for (int ci=0; ci<12; ++ci) {
    const float* pin = x + (size_t)(bg*12+ci)*NSPA;
    for (int kh=0;kh<3;kh++){
      int hh=h+kh-1; if ((unsigned)hh>=32u) continue;
      for (int kw=0;kw<3;kw++){
        int ww=w+kw-1; if ((unsigned)ww>=32u) continue;
        for (int kd=0;kd<3;kd++){
          int dd=d+kd-1; if ((unsigned)dd>=32u) continue;
          float v = pin[hh*1024+ww*32+dd];
          const float* wp = &sw[ci*27 + kh*9+kw*3+kd];
          #pragma unroll
          for (int co=0;co<12;co++) acc[co] += wp[co*324]*v;
        }
      }
    }
  }
  for (int co=0;co<12;co++){
    float r = acc[co]+sb[co];
    x2[(size_t)(bg*12+co)*NSPA + l] = r;
    float rv = r;
    #pragma unroll
    for (int m=32;m>=1;m>>=1) rv += __shfl_xor(rv,m);
    if ((threadIdx.x&63)==0) atomicAdd(&ssum[co], rv);
  }
  __syncthreads();
  if (threadIdx.x<12) atomicAdd(&st[ST_X2SUM + bg*12 + threadIdx.x], ssum[threadIdx.x]);
}

// ============ K5: SPPE attention weights + y_sppe ============
// grid (128, 16), block 256
__global__ void k_sppe_out(const float* __restrict__ x, const float* __restrict__ gated,
                           const float* __restrict__ x2, const float* __restrict__ gnw,
                           const float* __restrict__ gnb, const float* __restrict__ st,
                           float* __restrict__ ysppe) {
  int bg = blockIdx.y; int b = bg>>3; int g = bg&7;
  __shared__ float x11s[12], alphas[12], betasum_s;
  if (threadIdx.x==0){
    // x11 = softmax(mean(x1)) ; mean(x1) == gn_b exactly
    float m1=-1e30f, m2=-1e30f;
    float mu2[12];
    for (int cg=0;cg<12;cg++){
      int bc=b*96+g*12+cg;
      mu2[cg] = st[ST_X2SUM+bc]*(1.f/(float)NSPA);
      m1 = fmaxf(m1, gnb[cg]); m2 = fmaxf(m2, mu2[cg]);
    }
    float e1[12], e2[12]; float s1=0.f, s2=0.f;
    for (int cg=0;cg<12;cg++){ e1[cg]=expf(gnb[cg]-m1); s1+=e1[cg];
                               e2[cg]=expf(mu2[cg]-m2); s2+=e2[cg]; }
    float bs=0.f;
    for (int cg=0;cg<12;cg++){
      int bc=b*96+g*12+cg;
      float x11 = e1[cg]/s1;
      float x21 = e2[cg]/s2;
      x11s[cg]=x11;
      float gr = st[ST_GRSTD+bc], gm = st[ST_GM+bc];
      alphas[cg] = x21*gr*gnw[cg];
      bs += x21*(gnb[cg] - gm*gr*gnw[cg]);
    }
    betasum_s = bs;
  }
  __syncthreads();
  int l = blockIdx.x*256 + threadIdx.x;
  float wsum = betasum_s;
  int bc0 = b*96+g*12;
  for (int cg=0;cg<12;cg++){
    size_t off = (size_t)(bc0+cg)*NSPA + l;
    wsum += x11s[cg]*x2[off] + alphas[cg]*gated[off];
  }
  float sig = sigmoidf_(wsum);
  for (int cg=0;cg<12;cg++){
    size_t off = (size_t)(bc0+cg)*NSPA + l;
    ysppe[off] = x[off]*sig;
  }
}

// ============ generic channel-major GEMM: out[o,l] = sum_k W[o,k]*A[k,l] ============
// grid (512, b), block 256; A is (b, K, NSPA); optional per-(b,k) normalization of A.
template<int K, int O>
__global__ void k_gemm(const float* __restrict__ A, const float* __restrict__ W,
                       float* __restrict__ out0, float* __restrict__ out1,
                       int splitO, int orows,
                       const float* __restrict__ mean, const float* __restrict__ rstd) {
  __shared__ float As[K*64];
  int b = blockIdx.y; int l0 = blockIdx.x*64; int tid = threadIdx.x;
  for (int i=tid;i<K*64;i+=256){
    int k=i>>6, l=i&63;
    float v = A[((size_t)b*K+k)*NSPA + l0+l];
    if (mean) v = (v-mean[b*K+k])*rstd[b*K+k];
    As[i]=v;
  }
  __syncthreads();
  int l4=(tid&15)*4; int og=tid>>4;
  for (int o0=og*4; o0<O; o0+=64){
    float acc[16];
    #pragma unroll
    for (int i=0;i<16;i++) acc[i]=0.f;
    for (int k=0;k<K;k++){
      float4 a = *(const float4*)&As[k*64+l4];
      #pragma unroll
      for (int j=0;j<4;j++){
        int o=o0+j;
        float wv = (o<O) ? W[(size_t)o*K+k] : 0.f;
        acc[j*4+0]+=wv*a.x; acc[j*4+1]+=wv*a.y; acc[j*4+2]+=wv*a.z; acc[j*4+3]+=wv*a.w;
      }
    }
    #pragma unroll
    for (int j=0;j<4;j++){
      int o=o0+j; if (o>=O) break;
      float* dst = out0; int oo=o;
      if (out1 && o>=splitO){ dst=out1; oo=o-splitO; }
      float4 r; r.x=acc[j*4+0]; r.y=acc[j*4+1]; r.z=acc[j*4+2]; r.w=acc[j*4+3];
      *(float4*)&dst[((size_t)b*orows+oo)*NSPA + l0+l4] = r;
    }
  }
}

// ============ K8: causal depthwise conv1d + silu ============
// grid 49152, block 256
__global__ void k_conv1d(const float* __restrict__ xm, const float* __restrict__ cw,
                         const float* __restrict__ cb, float* __restrict__ xc) {
  size_t idx = (size_t)blockIdx.x*256 + threadIdx.x;
  int l = (int)(idx & 32767);
  size_t be = idx >> 15;
  int e = (int)(be % 192);
  const float* row = xm + be*NSPA;
  float acc = cb[e];
  #pragma unroll
  for (int k=0;k<4;k++){
    int ll = l-3+k;
    if (ll>=0) acc += cw[e*4+k]*row[ll];
  }
  xc[idx] = siluf_(acc);
}

// ============ K10: dt = softplus(dt_proj(dbl[:6])) ============
// grid (128, 384), block 256
__global__ void k_dt(const float* __restrict__ dbl, const float* __restrict__ dtw,
                     const float* __restrict__ dtb, float* __restrict__ dt) {
  int b = blockIdx.y/192; int e = blockIdx.y%192;
  int l = blockIdx.x*256 + threadIdx.x;
  float acc = dtb[e];
  #pragma unroll
  for (int j=0;j<6;j++)
    acc += dtw[e*6+j]*dbl[((size_t)b*38+j)*NSPA + l];
  dt[((size_t)b*192+e)*NSPA + l] = softplusf_(acc);
}

// ============ scan phase A: per-chunk products + local end states ============
// grid (128 chunks, 12 e-blocks, 2 b), block 256 (16 e x 16 n)
__global__ void k_scanA(const float* __restrict__ dt, const float* __restrict__ xc,
                        const float* __restrict__ dbl, const float* __restrict__ A_log,
                        float* __restrict__ P, float* __restrict__ hend) {
  int b = blockIdx.z, eb = blockIdx.y, ch = blockIdx.x;
  int t = threadIdx.x; int e = eb*16 + (t>>4); int n = t&15;
  float Ae = -expf(A_log[e*16+n]);
  size_t rowdt = ((size_t)b*192+e)*NSPA + ch*256;
  const float4* pdt = (const float4*)(dt + rowdt);
  const float4* px  = (const float4*)(xc + rowdt);
  const float4* pB  = (const float4*)(dbl + ((size_t)b*38+6+n)*NSPA + ch*256);
  float h=0.f, Pp=1.f;
  for (int i=0;i<64;i++){
    float4 d4=pdt[i], x4=px[i], b4=pB[i];
    float a;
    a=expf(d4.x*Ae); Pp*=a; h=h*a + d4.x*x4.x*b4.x;
    a=expf(d4.y*Ae); Pp*=a; h=h*a + d4.y*x4.y*b4.y;
    a=expf(d4.z*Ae); Pp*=a; h=h*a + d4.z*x4.z*b4.z;
    a=expf(d4.w*Ae); Pp*=a; h=h*a + d4.w*x4.w*b4.w;
  }
  size_t idx = (((size_t)b*128+ch)*192+e)*16 + n;
  P[idx]=Pp; hend[idx]=h;
}

// ============ scan phase B: sequential inter-chunk combine ============
// grid 24, block 256 (6144 threads = b*e*n)
__global__ void k_scanB(const float* __restrict__ P, const float* __restrict__ hend,
                        float* __restrict__ Hs) {
  int t = blockIdx.x*256 + threadIdx.x;
  int b = t / 3072; int r = t % 3072;
  float H = 0.f;
  size_t base = (size_t)b*128*3072 + r;
  for (int c=0;c<128;c++){
    size_t idx = base + (size_t)c*3072;
    Hs[idx] = H;
    H = P[idx]*H + hend[idx];
  }
}

// ============ scan phase C: seeded re-scan, fused y epilogue ============
// NOTE: y aliases xc (in-place). Safe: every lane of the 16-lane state group
// (same wave) loads x4 = xc[i] before lane n==0 stores y[i]; no __restrict__
// on xc/y so the compiler preserves load-before-store order.
__global__ void k_scanC(const float* __restrict__ dt, const float* xc,
                        const float* __restrict__ dbl, const float* __restrict__ A_log,
                        const float* __restrict__ Hs, const float* __restrict__ ssm_D,
                        const float* __restrict__ zg, float* y) {
  int b = blockIdx.z, eb = blockIdx.y, ch = blockIdx.x;
  int t = threadIdx.x; int e = eb*16 + (t>>4); int n = t&15;
  float Ae = -expf(A_log[e*16+n]);
  float Dv = ssm_D[e];
  size_t rowdt = ((size_t)b*192+e)*NSPA + ch*256;
  const float4* pdt = (const float4*)(dt + rowdt);
  const float4* px  = (const float4*)(xc + rowdt);
  const float4* pz  = (const float4*)(zg + rowdt);
  const float4* pB  = (const float4*)(dbl + ((size_t)b*38+6+n)*NSPA + ch*256);
  const float4* pC  = (const float4*)(dbl + ((size_t)b*38+22+n)*NSPA + ch*256);
  float4* py = (float4*)(y + rowdt);
  float h = Hs[(((size_t)b*128+ch)*192+e)*16 + n];
  for (int i=0;i<64;i++){
    float4 d4=pdt[i], x4=px[i], b4=pB[i], c4=pC[i], z4=pz[i];
    float4 o4;
    float a, yp;
    a=expf(d4.x*Ae); h=h*a + d4.x*x4.x*b4.x; yp=h*c4.x;
    yp+=__shfl_xor(yp,1); yp+=__shfl_xor(yp,2); yp+=__shfl_xor(yp,4); yp+=__shfl_xor(yp,8);
    o4.x = (yp + x4.x*Dv)*siluf_(z4.x);
    a=expf(d4.y*Ae); h=h*a + d4.y*x4.y*b4.y; yp=h*c4.y;
    yp+=__shfl_xor(yp,1); yp+=__shfl_xor(yp,2); yp+=__shfl_xor(yp,4); yp+=__shfl_xor(yp,8);
    o4.y = (yp + x4.y*Dv)*siluf_(z4.y);
    a=expf(d4.z*Ae); h=h*a + d4.z*x4.z*b4.z; yp=h*c4.z;
    yp+=__shfl_xor(yp,1); yp+=__shfl_xor(yp,2); yp+=__shfl_xor(yp,4); yp+=__shfl_xor(yp,8);
    o4.z = (yp + x4.z*Dv)*siluf_(z4.z);
    a=expf(d4.w*Ae); h=h*a + d4.w*x4.w*b4.w; yp=h*c4.w;
    yp+=__shfl_xor(yp,1); yp+=__shfl_xor(yp,2); yp+=__shfl_xor(yp,4); yp+=__shfl_xor(yp,8);
    o4.w = (yp + x4.w*Dv)*siluf_(z4.w);
    if (n==0) py[i] = o4;
  }
}

// ============ K15: instance-norm stats of `out` ============
// grid 192, block 256
__global__ void k_stats2(const float* __restrict__ outb, float* __restrict__ st) {
  int bc = blockIdx.x; int t = threadIdx.x;
  const float* p = outb + (size_t)bc*NSPA;
  float s=0.f, s2=0.f;
  for (int i=t;i<NSPA;i+=256){ float v=p[i]; s+=v; s2+=v*v; }
  __shared__ float red[4], red2[4];
  #pragma unroll
  for (int m=32;m>=1;m>>=1){ s += __shfl_xor(s,m); s2 += __shfl_xor(s2,m); }
  if ((t&63)==0){ red[t>>6]=s; red2[t>>6]=s2; }
  __syncthreads();
  if (t==0){
    float S=red[0]+red[1]+red[2]+red[3];
    float S2=red2[0]+red2[1]+red2[2]+red2[3];
    float mn=S/(float)NSPA; float var=S2/(float)NSPA-mn*mn;
    st[ST_MEAN2+bc]=mn; st[ST_RSTD2+bc]=rsqrtf(var+EPS);
  }
}

// ============ K16: fused xo-norm * y_sppe -> fc1 -> gelu -> fc2 -> +x ============
// grid (1024, 2), block 256; LDS 60KB
__global__ void k_mlp(const float* __restrict__ outb, const float* __restrict__ ysppe,
                      const float* __restrict__ x, const float* __restrict__ st,
                      const float* __restrict__ W1, const float* __restrict__ b1,
                      const float* __restrict__ W2, const float* __restrict__ b2,
                      float* __restrict__ dout) {
  __shared__ float xoS[96*32];
  __shared__ float hid[384*32];
  int b = blockIdx.y; int l0 = blockIdx.x*32; int tid = threadIdx.x;
  for (int i=tid;i<96*32;i+=256){
    int k=i>>5, l=i&31;
    size_t off = ((size_t)b*96+k)*NSPA + l0+l;
    xoS[i] = (outb[off]-st[ST_MEAN2+b*96+k])*st[ST_RSTD2+b*96+k]*ysppe[off];
  }
  __syncthreads();
  int l4=(tid&7)*4; int og=tid>>3; // og in [0,32)
  for (int o0=og*4; o0<384; o0+=128){
    float acc[16];
    #pragma unroll
    for (int i=0;i<16;i++) acc[i]=0.f;
    for (int k=0;k<96;k++){
      float4 a = *(const float4*)&xoS[k*32+l4];
      #pragma unroll
      for (int j=0;j<4;j++){
        float wv = W1[(size_t)(o0+j)*96+k];
        acc[j*4+0]+=wv*a.x; acc[j*4+1]+=wv*a.y; acc[j*4+2]+=wv*a.z; acc[j*4+3]+=wv*a.w;
      }
    }
    #pragma unroll
    for (int j=0;j<4;j++){
      int o=o0+j; float bias=b1[o];
      hid[o*32+l4+0]=geluf_(acc[j*4+0]+bias);
      hid[o*32+l4+1]=geluf_(acc[j*4+1]+bias);
      hid[o*32+l4+2]=geluf_(acc[j*4+2]+bias);
      hid[o*32+l4+3]=geluf_(acc[j*4+3]+bias);
    }
  }
  __syncthreads();
  for (int o0=og*4; o0<96; o0+=128){ // og<24 active
    float acc[16];
    #pragma unroll
    for (int i=0;i<16;i++) acc[i]=0.f;
    for (int k=0;k<384;k++){
      float4 a = *(const float4*)&hid[k*32+l4];
      #pragma unroll
      for (int j=0;j<4;j++){
        float wv = W2[(size_t)(o0+j)*384+k];
        acc[j*4+0]+=wv*a.x; acc[j*4+1]+=wv*a.y; acc[j*4+2]+=wv*a.z; acc[j*4+3]+=wv*a.w;
      }
    }
    #pragma unroll
    for (int j=0;j<4;j++){
      int o=o0+j;
      size_t off = ((size_t)b*96+o)*NSPA + l0+l4;
      float4 xin = *(const float4*)&x[off];
      float4 r;
      r.x=acc[j*4+0]+b2[o]+xin.x; r.y=acc[j*4+1]+b2[o]+xin.y;
      r.z=acc[j*4+2]+b2[o]+xin.z; r.w=acc[j*4+3]+b2[o]+xin.w;
      *(float4*)&dout[off] = r;
    }
  }
}

extern "C" void kernel_launch(void* const* d_in, const int* in_sizes, int n_in,
                              void* d_out, int out_size, void* d_ws, size_t ws_size,
                              hipStream_t stream) {
  const float* x        = (const float*)d_in[0];
  const float* c1w      = (const float*)d_in[1];
  const float* c1b      = (const float*)d_in[2];
  const float* c3w      = (const float*)d_in[3];
  const float* c3b      = (const float*)d_in[4];
  const float* gnw      = (const float*)d_in[5];
  const float* gnb      = (const float*)d_in[6];
  const float* in_proj  = (const float*)d_in[7];
  const float* conv1dw  = (const float*)d_in[8];
  const float* conv1db  = (const float*)d_in[9];
  const float* xprojw   = (const float*)d_in[10];
  const float* dtw      = (const float*)d_in[11];
  const float* dtb      = (const float*)d_in[12];
  const float* A_log    = (const float*)d_in[13];
  const float* ssm_D    = (const float*)d_in[14];
  const float* outprojw = (const float*)d_in[15];
  const float* W1       = (const float*)d_in[16];
  const float* b1       = (const float*)d_in[17];
  const float* W2       = (const float*)d_in[18];
  const float* b2       = (const float*)d_in[19];
  float* dout = (float*)d_out;

  float* ws = (float*)d_ws;
  // ---- compact arena with region aliasing; peak = 56,688,640 floats = 216.3 MiB ----
  // R_A: xm -> dt            (12.58M)
  // R_B: zg                  (12.58M)
  // R_C: xc -> y (in-place)  (12.58M)
  // R_D: gated -> dbl + P/hend/Hs   (6.29M)
  // R_E: x2 -> outb          (6.29M)
  // R_F: ysppe               (6.29M)
  const size_t o_st = 0;                        // 65536 floats
  const size_t o_A  = 65536;
  const size_t o_B  = o_A + 12582912;
  const size_t o_C  = o_B + 12582912;
  const size_t o_D  = o_C + 12582912;
  const size_t o_E  = o_D + 6291456;
  const size_t o_F  = o_E + 6291456;
  float* st    = ws + o_st;
  float* xm    = ws + o_A;
  float* dt    = ws + o_A;        // after conv1d, xm dead
  float* zg    = ws + o_B;
  float* xc    = ws + o_C;
  float* yb    = ws + o_C;        // scanC writes y in-place over xc
  float* gated = ws + o_D;
  float* dbl   = ws + o_D;        // after sppe_out, gated dead
  float* P     = ws + o_D + 2490368;
  float* hend  = ws + o_D + 2490368 + 786432;
  float* Hs    = ws + o_D + 2490368 + 1572864;
  float* x2b   = ws + o_E;
  float* outb  = ws + o_E;        // after sppe_out, x2 dead
  float* ysppe = ws + o_F;

  hipMemsetAsync(st, 0, 65536*sizeof(float), stream);

  // --- instance-norm stats of x + pooled means ---
  k_stats<<<192, 1024, 0, stream>>>(x, st);
  // --- SPPE gates ---
  k_gates<<<16, 128, 0, stream>>>(c1w, c1b, st);
  // --- gated tensor + group stats ---
  k_gated<<<192, 1024, 0, stream>>>(x, gated, st);
  // --- 3x3x3 grouped conv + channel sums ---
  k_conv3<<<dim3(128,16), 256, 0, stream>>>(x, c3w, c3b, x2b, st);
  // --- SPPE output ---
  k_sppe_out<<<dim3(128,16), 256, 0, stream>>>(x, gated, x2b, gnw, gnb, st, ysppe);
  // --- in_proj (with fused inorm of x): xm, zg ---
  k_gemm<96,384><<<dim3(512,2), 256, 0, stream>>>(x, in_proj, xm, zg, 192, 192,
                                                  st+ST_MEAN, st+ST_RSTD);
  // --- causal depthwise conv1d + silu ---
  k_conv1d<<<49152, 256, 0, stream>>>(xm, conv1dw, conv1db, xc);
  // --- x_proj -> dbl (rows 0..5 dt-in, 6..21 B, 22..37 C) ---
  k_gemm<192,38><<<dim3(512,2), 256, 0, stream>>>(xc, xprojw, dbl, nullptr, 1<<30, 38,
                                                  nullptr, nullptr);
  // --- dt projection + softplus (into dead xm region) ---
  k_dt<<<dim3(128,384), 256, 0, stream>>>(dbl, dtw, dtb, dt);
  // --- chunked selective scan ---
  k_scanA<<<dim3(128,12,2), 256, 0, stream>>>(dt, xc, dbl, A_log, P, hend);
  k_scanB<<<24, 256, 0, stream>>>(P, hend, Hs);
  k_scanC<<<dim3(128,12,2), 256, 0, stream>>>(dt, xc, dbl, A_log, Hs, ssm_D, zg, yb);
  // --- out_proj (into dead x2 region) ---
  k_gemm<192,96><<<dim3(512,2), 256, 0, stream>>>(yb, outprojw, outb, nullptr, 1<<30, 96,
                                                  nullptr, nullptr);
  // --- inorm stats of out ---
  k_stats2<<<192, 256, 0, stream>>>(outb, st);
  // --- fused xo = inorm(out)*ysppe -> MLP -> +x ---
  k_mlp<<<dim3(1024,2), 256, 0, stream>>>(outb, ysppe, x, st, W1, b1, W2, b2, dout);
}

// Round 3
// 1081.851 us; speedup vs baseline: 1.2238x; 1.2238x over previous
//
#include <hip/hip_runtime.h>
#include <math.h>

#define NSPA 32768           // 32*32*32 spatial positions = L
#define TCH 128              // scan chunk length
#define NCH 256              // number of chunks = NSPA/TCH
#define EPS 1e-5f

// ---- stats arena offsets (floats, within d_ws[0..65535]) ----
#define ST_MEAN   0      // 192
#define ST_RSTD   192    // 192
#define ST_GM     384    // 192
#define ST_GRSTD  576    // 192
#define ST_X2SUM  768    // 192
#define ST_XH     1024   // 192*32
#define ST_XW     7168   // 192*32
#define ST_XD     13312  // 192*32
#define ST_GATE   19456  // 16*12*96 = 18432
#define ST_MEAN2  38400  // 192
#define ST_RSTD2  38592  // 192

__device__ __forceinline__ float sigmoidf_(float x){ return 1.f/(1.f+__expf(-x)); }
__device__ __forceinline__ float siluf_(float x){ return x/(1.f+__expf(-x)); }
__device__ __forceinline__ float geluf_(float x){ return 0.5f*x*(1.f+erff(x*0.70710678118654752f)); }
__device__ __forceinline__ float softplusf_(float x){ return fmaxf(x,0.f) + log1pf(__expf(-fabsf(x))); }

// ============ K1: per-(b,c) instance-norm stats + SPPE pooled means ============
// grid 192, block 1024
__global__ void k_stats(const float* __restrict__ x, float* __restrict__ st) {
  int bc = blockIdx.x;
  int t = threadIdx.x;
  __shared__ float xh_s[32], xw_s[32], xd_s[32], red[16], red2[16];
  if (t < 32) { xh_s[t]=0.f; xw_s[t]=0.f; xd_s[t]=0.f; }
  __syncthreads();
  const float* px = x + (size_t)bc*NSPA;
  float s=0.f, s2=0.f;
  for (int it=0; it<32; ++it) {
    float v = px[it*1024 + t];
    s += v; s2 += v*v;
    float wv = v;
    #pragma unroll
    for (int m=32;m>=1;m>>=1) wv += __shfl_xor(wv,m);
    if ((t&63)==0) atomicAdd(&xh_s[it], wv);
  }
  atomicAdd(&xw_s[(t>>5)&31], s);
  atomicAdd(&xd_s[t&31], s);
  float rs=s, rs2=s2;
  #pragma unroll
  for (int m=32;m>=1;m>>=1){ rs += __shfl_xor(rs,m); rs2 += __shfl_xor(rs2,m); }
  if ((t&63)==0){ red[t>>6]=rs; red2[t>>6]=rs2; }
  __syncthreads();
  if (t==0){
    float S=0.f,S2=0.f;
    for (int w=0;w<16;w++){ S+=red[w]; S2+=red2[w]; }
    float mn = S/(float)NSPA;
    float var = S2/(float)NSPA - mn*mn;
    st[ST_MEAN+bc] = mn;
    st[ST_RSTD+bc] = rsqrtf(var+EPS);
  }
  if (t<32){
    st[ST_XH + bc*32 + t] = xh_s[t]*(1.f/1024.f);
    st[ST_XW + bc*32 + t] = xw_s[t]*(1.f/1024.f);
    st[ST_XD + bc*32 + t] = xd_s[t]*(1.f/1024.f);
  }
}

// ============ K2: SPPE 1x1 conv on pooled vectors -> sigmoid gates ============
__global__ void k_gates(const float* __restrict__ c1w, const float* __restrict__ c1b,
                        float* __restrict__ st) {
  int bg = blockIdx.x; int b = bg>>3; int g = bg&7;
  for (int i = threadIdx.x; i < 12*96; i += 128) {
    int co = i/96, pos = i%96;
    float acc = c1b[co];
    for (int cg=0; cg<12; ++cg) {
      int bc = b*96 + g*12 + cg;
      float hv;
      if (pos < 32)      hv = st[ST_XH + bc*32 + pos];
      else if (pos < 64) hv = st[ST_XW + bc*32 + pos-32];
      else               hv = st[ST_XD + bc*32 + pos-64];
      acc += c1w[co*12+cg]*hv;
    }
    st[ST_GATE + bg*1152 + i] = sigmoidf_(acc);
  }
}

// ============ K3: gated = gx*gh*gw*gd, + group-norm stats ============
__global__ void k_gated(const float* __restrict__ x, float* __restrict__ gated,
                        float* __restrict__ st) {
  int bc = blockIdx.x; int bg = bc/12; int cg = bc%12;
  int t = threadIdx.x;
  const float* gate = st + ST_GATE + bg*1152 + cg*96;
  float gw = gate[32 + (t>>5)];
  float gd = gate[64 + (t&31)];
  const float* px = x + (size_t)bc*NSPA;
  float* pg = gated + (size_t)bc*NSPA;
  __shared__ float red[16], red2[16];
  float s=0.f, s2=0.f;
  for (int it=0; it<32; ++it) {
    float gh = gate[it];
    float v = px[it*1024+t]*gh*gw*gd;
    pg[it*1024+t] = v;
    s += v; s2 += v*v;
  }
  #pragma unroll
  for (int m=32;m>=1;m>>=1){ s += __shfl_xor(s,m); s2 += __shfl_xor(s2,m); }
  if ((t&63)==0){ red[t>>6]=s; red2[t>>6]=s2; }
  __syncthreads();
  if (t==0){
    float S=0.f,S2=0.f;
    for (int w=0;w<16;w++){ S+=red[w]; S2+=red2[w]; }
    float mn = S/(float)NSPA;
    float var = S2/(float)NSPA - mn*mn;
    st[ST_GM+bc] = mn;
    st[ST_GRSTD+bc] = rsqrtf(var+EPS);
  }
}

// ============ K4: grouped 3x3x3 conv (x2) + per-channel spatial sums ============
__global__ void k_conv3(const float* __restrict__ x, const float* __restrict__ c3w,
                        const float* __restrict__ c3b, float* __restrict__ x2,
                        float* __restrict__ st) {
  int bg = blockIdx.y;
  int l = blockIdx.x*256 + threadIdx.x;
  int h = l>>10, w = (l>>5)&31, d = l&31;
  __shared__ float sw[3888];
  __shared__ float sb[12], ssum[12];
  for (int i=threadIdx.x;i<3888;i+=256) sw[i]=c3w[i];
  if (threadIdx.x<12){ sb[threadIdx.x]=c3b[threadIdx.x]; ssum[threadIdx.x]=0.f; }
  __syncthreads();
  float acc[12];
  #pragma unroll
  for (int co=0;co<12;co++) acc[co]=0.f;
  for (int ci=0; ci<12; ++ci) {
    const float* pin = x + (size_t)(bg*12+ci)*NSPA;
    for (int kh=0;kh<3;kh++){
      int hh=h+kh-1; if ((unsigned)hh>=32u) continue;
      for (int kw=0;kw<3;kw++){
        int ww=w+kw-1; if ((unsigned)ww>=32u) continue;
        for (int kd=0;kd<3;kd++){
          int dd=d+kd-1; if ((unsigned)dd>=32u) continue;
          float v = pin[hh*1024+ww*32+dd];
          const float* wp = &sw[ci*27 + kh*9+kw*3+kd];
          #pragma unroll
          for (int co=0;co<12;co++) acc[co] += wp[co*324]*v;
        }
      }
    }
  }
  for (int co=0;co<12;co++){
    float r = acc[co]+sb[co];
    x2[(size_t)(bg*12+co)*NSPA + l] = r;
    float rv = r;
    #pragma unroll
    for (int m=32;m>=1;m>>=1) rv += __shfl_xor(rv,m);
    if ((threadIdx.x&63)==0) atomicAdd(&ssum[co], rv);
  }
  __syncthreads();
  if (threadIdx.x<12) atomicAdd(&st[ST_X2SUM + bg*12 + threadIdx.x], ssum[threadIdx.x]);
}

// ============ K5: SPPE attention weights + y_sppe ============
__global__ void k_sppe_out(const float* __restrict__ x, const float* __restrict__ gated,
                           const float* __restrict__ x2, const float* __restrict__ gnw,
                           const float* __restrict__ gnb, const float* __restrict__ st,
                           float* __restrict__ ysppe) {
  int bg = blockIdx.y; int b = bg>>3; int g = bg&7;
  __shared__ float x11s[12], alphas[12], betasum_s;
  if (threadIdx.x==0){
    float m1=-1e30f, m2=-1e30f;
    float mu2[12];
    for (int cg=0;cg<12;cg++){
      int bc=b*96+g*12+cg;
      mu2[cg] = st[ST_X2SUM+bc]*(1.f/(float)NSPA);
      m1 = fmaxf(m1, gnb[cg]); m2 = fmaxf(m2, mu2[cg]);
    }
    float e1[12], e2[12]; float s1=0.f, s2=0.f;
    for (int cg=0;cg<12;cg++){ e1[cg]=expf(gnb[cg]-m1); s1+=e1[cg];
                               e2[cg]=expf(mu2[cg]-m2); s2+=e2[cg]; }
    float bs=0.f;
    for (int cg=0;cg<12;cg++){
      int bc=b*96+g*12+cg;
      float x11 = e1[cg]/s1;
      float x21 = e2[cg]/s2;
      x11s[cg]=x11;
      float gr = st[ST_GRSTD+bc], gm = st[ST_GM+bc];
      alphas[cg] = x21*gr*gnw[cg];
      bs += x21*(gnb[cg] - gm*gr*gnw[cg]);
    }
    betasum_s = bs;
  }
  __syncthreads();
  int l = blockIdx.x*256 + threadIdx.x;
  float wsum = betasum_s;
  int bc0 = b*96+g*12;
  for (int cg=0;cg<12;cg++){
    size_t off = (size_t)(bc0+cg)*NSPA + l;
    wsum += x11s[cg]*x2[off] + alphas[cg]*gated[off];
  }
  float sig = sigmoidf_(wsum);
  for (int cg=0;cg<12;cg++){
    size_t off = (size_t)(bc0+cg)*NSPA + l;
    ysppe[off] = x[off]*sig;
  }
}

// ============ in_proj GEMM: A e-major (x, fused inorm) -> token-major xm_t, zg_t ======
// grid (512, 2), block 256
__global__ void k_gemm_in(const float* __restrict__ A, const float* __restrict__ W,
                          float* __restrict__ xm_t, float* __restrict__ zg_t,
                          const float* __restrict__ mean, const float* __restrict__ rstd) {
  __shared__ float As[96*64];
  int b = blockIdx.y; int l0 = blockIdx.x*64; int tid = threadIdx.x;
  for (int i=tid;i<96*64;i+=256){
    int k=i>>6, l=i&63;
    float v = A[((size_t)b*96+k)*NSPA + l0+l];
    As[i] = (v-mean[b*96+k])*rstd[b*96+k];
  }
  __syncthreads();
  int l4=(tid&15)*4; int og=tid>>4;
  for (int o0=og*4; o0<384; o0+=64){
    float acc[16];
    #pragma unroll
    for (int i=0;i<16;i++) acc[i]=0.f;
    for (int k=0;k<96;k++){
      float4 a = *(const float4*)&As[k*64+l4];
      #pragma unroll
      for (int j=0;j<4;j++){
        float wv = W[(size_t)(o0+j)*96+k];
        acc[j*4+0]+=wv*a.x; acc[j*4+1]+=wv*a.y; acc[j*4+2]+=wv*a.z; acc[j*4+3]+=wv*a.w;
      }
    }
    #pragma unroll
    for (int i=0;i<4;i++){
      int l = l0+l4+i;
      float4 r; r.x=acc[0*4+i]; r.y=acc[1*4+i]; r.z=acc[2*4+i]; r.w=acc[3*4+i];
      if (o0 < 192) *(float4*)&xm_t[((size_t)b*NSPA + l)*192 + o0] = r;
      else          *(float4*)&zg_t[((size_t)b*NSPA + l)*192 + (o0-192)] = r;
    }
  }
}

// ============ conv1d + silu, token-major in/out ============
// grid (256, 2), block 192 (lane = e)
__global__ void k_conv1d_t(const float* __restrict__ xm_t, const float* __restrict__ cw,
                           const float* __restrict__ cb, float* __restrict__ xc_t) {
  int b = blockIdx.y; int l0 = blockIdx.x*128; int e = threadIdx.x;
  float4 w4 = *(const float4*)&cw[e*4];
  float bias = cb[e];
  const float* base = xm_t + (size_t)b*NSPA*192 + e;
  float* out = xc_t + (size_t)b*NSPA*192 + e;
  float hm3 = (l0>0) ? base[(size_t)(l0-3)*192] : 0.f;
  float hm2 = (l0>0) ? base[(size_t)(l0-2)*192] : 0.f;
  float hm1 = (l0>0) ? base[(size_t)(l0-1)*192] : 0.f;
  for (int l=0;l<128;l++){
    float cur = base[(size_t)(l0+l)*192];
    float acc = bias + w4.x*hm3 + w4.y*hm2 + w4.z*hm1 + w4.w*cur;
    out[(size_t)(l0+l)*192] = siluf_(acc);
    hm3=hm2; hm2=hm1; hm1=cur;
  }
}

// ============ x_proj GEMM: A token-major (xc_t) -> dbl_t token-major [l][40] ==========
// slot layout per l: [0..15]=B, [16..31]=C, [32..37]=dt-in, [38..39]=pad
// weight row perm: slot o<32 -> xprojw row o+6 ; slot 32..37 -> row o-32
// grid (512, 2), block 256
__global__ void k_gemm_xp(const float* __restrict__ A, const float* __restrict__ W,
                          float* __restrict__ dbl_t) {
  __shared__ float As[192*64];
  int b = blockIdx.y; int l0 = blockIdx.x*64; int tid = threadIdx.x;
  for (int f=tid; f<48*64; f+=256){
    int l = f&63, kq = f>>6;
    float4 v = *(const float4*)&A[((size_t)b*NSPA + l0+l)*192 + kq*4];
    As[(kq*4+0)*64+l]=v.x; As[(kq*4+1)*64+l]=v.y;
    As[(kq*4+2)*64+l]=v.z; As[(kq*4+3)*64+l]=v.w;
  }
  __syncthreads();
  int l4=(tid&15)*4; int og=tid>>4;
  for (int o0=og*4; o0<40; o0+=64){
    float acc[16];
    #pragma unroll
    for (int i=0;i<16;i++) acc[i]=0.f;
    for (int k=0;k<192;k++){
      float4 a = *(const float4*)&As[k*64+l4];
      #pragma unroll
      for (int j=0;j<4;j++){
        int o = o0+j;
        int row = (o<32) ? (o+6) : (o-32);
        float wv = (o<38) ? W[(size_t)row*192+k] : 0.f;
        acc[j*4+0]+=wv*a.x; acc[j*4+1]+=wv*a.y; acc[j*4+2]+=wv*a.z; acc[j*4+3]+=wv*a.w;
      }
    }
    #pragma unroll
    for (int i=0;i<4;i++){
      int l = l0+l4+i;
      float4 r; r.x=acc[0*4+i]; r.y=acc[1*4+i]; r.z=acc[2*4+i]; r.w=acc[3*4+i];
      *(float4*)&dbl_t[((size_t)b*NSPA + l)*40 + o0] = r;
    }
  }
}

// ============ out_proj GEMM: A token-major (y_t) -> e-major outb ============
// grid (512, 2), block 256
__global__ void k_gemm_out(const float* __restrict__ A, const float* __restrict__ W,
                           float* __restrict__ out) {
  __shared__ float As[192*64];
  int b = blockIdx.y; int l0 = blockIdx.x*64; int tid = threadIdx.x;
  for (int f=tid; f<48*64; f+=256){
    int l = f&63, kq = f>>6;
    float4 v = *(const float4*)&A[((size_t)b*NSPA + l0+l)*192 + kq*4];
    As[(kq*4+0)*64+l]=v.x; As[(kq*4+1)*64+l]=v.y;
    As[(kq*4+2)*64+l]=v.z; As[(kq*4+3)*64+l]=v.w;
  }
  __syncthreads();
  int l4=(tid&15)*4; int og=tid>>4;
  for (int o0=og*4; o0<96; o0+=64){
    float acc[16];
    #pragma unroll
    for (int i=0;i<16;i++) acc[i]=0.f;
    for (int k=0;k<192;k++){
      float4 a = *(const float4*)&As[k*64+l4];
      #pragma unroll
      for (int j=0;j<4;j++){
        float wv = W[(size_t)(o0+j)*192+k];
        acc[j*4+0]+=wv*a.x; acc[j*4+1]+=wv*a.y; acc[j*4+2]+=wv*a.z; acc[j*4+3]+=wv*a.w;
      }
    }
    #pragma unroll
    for (int j=0;j<4;j++){
      int o=o0+j;
      float4 r; r.x=acc[j*4+0]; r.y=acc[j*4+1]; r.z=acc[j*4+2]; r.w=acc[j*4+3];
      *(float4*)&out[((size_t)b*96+o)*NSPA + l0+l4] = r;
    }
  }
}

// ============ scan phase A: lane = e, 16 states in registers ============
// grid (NCH, 2), block 192.  Fuses dt = softplus(dt_proj(...)) inline.
__global__ void k_scanA(const float* __restrict__ xc_t, const float* __restrict__ dbl_t,
                        const float* __restrict__ dtw, const float* __restrict__ dtb,
                        const float* __restrict__ A_log,
                        float* __restrict__ P, float* __restrict__ hend) {
  int b = blockIdx.y, ch = blockIdx.x; int e = threadIdx.x;
  float An[16];
  #pragma unroll
  for (int n=0;n<16;n++) An[n] = -__expf(A_log[e*16+n]);
  float wdt[6];
  #pragma unroll
  for (int j=0;j<6;j++) wdt[j]=dtw[e*6+j];
  float bdt = dtb[e];
  const float* drow = dbl_t + ((size_t)b*NSPA + (size_t)ch*TCH)*40;
  const float* xrow = xc_t + ((size_t)b*NSPA + (size_t)ch*TCH)*192 + e;
  float h[16], Pp[16];
  #pragma unroll
  for (int n=0;n<16;n++){ h[n]=0.f; Pp[n]=1.f; }
  for (int l=0;l<TCH;l++){
    const float* u = drow + l*40;
    float4 b0=*(const float4*)(u+0), b1=*(const float4*)(u+4),
           b2=*(const float4*)(u+8), b3=*(const float4*)(u+12);
    float4 d4=*(const float4*)(u+32);
    float2 d2=*(const float2*)(u+36);
    float x = xrow[(size_t)l*192];
    float pre = bdt + wdt[0]*d4.x + wdt[1]*d4.y + wdt[2]*d4.z
                    + wdt[3]*d4.w + wdt[4]*d2.x + wdt[5]*d2.y;
    float dte = softplusf_(pre);
    float dtx = dte*x;
    float Bv[16] = {b0.x,b0.y,b0.z,b0.w, b1.x,b1.y,b1.z,b1.w,
                    b2.x,b2.y,b2.z,b2.w, b3.x,b3.y,b3.z,b3.w};
    #pragma unroll
    for (int n=0;n<16;n++){
      float a = __expf(dte*An[n]);
      Pp[n] *= a;
      h[n] = h[n]*a + dtx*Bv[n];
    }
  }
  size_t o = (((size_t)b*NCH+ch)*192+e)*16;
  #pragma unroll
  for (int q=0;q<4;q++){
    float4 rp; rp.x=Pp[q*4+0]; rp.y=Pp[q*4+1]; rp.z=Pp[q*4+2]; rp.w=Pp[q*4+3];
    *(float4*)&P[o+q*4] = rp;
    float4 rh; rh.x=h[q*4+0]; rh.y=h[q*4+1]; rh.z=h[q*4+2]; rh.w=h[q*4+3];
    *(float4*)&hend[o+q*4] = rh;
  }
}

// ============ scan phase B: sequential inter-chunk combine (prefetched) ============
// grid 24, block 256 (6144 threads = b * e * n)
__global__ void k_scanB(const float* __restrict__ P, const float* __restrict__ hend,
                        float* __restrict__ Hs) {
  int t = blockIdx.x*256 + threadIdx.x;
  int b = t / 3072; int r = t % 3072;
  size_t base = (size_t)b*NCH*3072 + r;
  float H = 0.f;
  float Pc = P[base], Hc = hend[base];
  for (int c=0;c<NCH;c++){
    size_t idx = base + (size_t)c*3072;
    float Pn=0.f, Hn=0.f;
    if (c+1<NCH){ Pn = P[idx+3072]; Hn = hend[idx+3072]; }
    Hs[idx] = H;
    H = fmaf(Pc, H, Hc);
    Pc = Pn; Hc = Hn;
  }
}

// ============ scan phase C: seeded re-scan + fused y epilogue, lane = e ============
// y_t aliases xc_t in-place (same thread reads x before storing y at same address).
// grid (NCH, 2), block 192.
__global__ void k_scanC(const float* xc_t, const float* __restrict__ dbl_t,
                        const float* __restrict__ dtw, const float* __restrict__ dtb,
                        const float* __restrict__ A_log, const float* __restrict__ Hs,
                        const float* __restrict__ ssm_D, const float* __restrict__ zg_t,
                        float* y_t) {
  int b = blockIdx.y, ch = blockIdx.x; int e = threadIdx.x;
  float An[16];
  #pragma unroll
  for (int n=0;n<16;n++) An[n] = -__expf(A_log[e*16+n]);
  float wdt[6];
  #pragma unroll
  for (int j=0;j<6;j++) wdt[j]=dtw[e*6+j];
  float bdt = dtb[e];
  float Dv = ssm_D[e];
  const float* drow = dbl_t + ((size_t)b*NSPA + (size_t)ch*TCH)*40;
  const float* xrow = xc_t + ((size_t)b*NSPA + (size_t)ch*TCH)*192 + e;
  const float* zrow = zg_t + ((size_t)b*NSPA + (size_t)ch*TCH)*192 + e;
  float* yrow = y_t + ((size_t)b*NSPA + (size_t)ch*TCH)*192 + e;
  float h[16];
  size_t ho = (((size_t)b*NCH+ch)*192+e)*16;
  #pragma unroll
  for (int q=0;q<4;q++){
    float4 hv = *(const float4*)&Hs[ho+q*4];
    h[q*4+0]=hv.x; h[q*4+1]=hv.y; h[q*4+2]=hv.z; h[q*4+3]=hv.w;
  }
  for (int l=0;l<TCH;l++){
    const float* u = drow + l*40;
    float4 b0=*(const float4*)(u+0), b1=*(const float4*)(u+4),
           b2=*(const float4*)(u+8), b3=*(const float4*)(u+12);
    float4 c0=*(const float4*)(u+16), c1=*(const float4*)(u+20),
           c2=*(const float4*)(u+24), c3=*(const float4*)(u+28);
    float4 d4=*(const float4*)(u+32);
    float2 d2=*(const float2*)(u+36);
    float x = xrow[(size_t)l*192];
    float z = zrow[(size_t)l*192];
    float pre = bdt + wdt[0]*d4.x + wdt[1]*d4.y + wdt[2]*d4.z
                    + wdt[3]*d4.w + wdt[4]*d2.x + wdt[5]*d2.y;
    float dte = softplusf_(pre);
    float dtx = dte*x;
    float Bv[16] = {b0.x,b0.y,b0.z,b0.w, b1.x,b1.y,b1.z,b1.w,
                    b2.x,b2.y,b2.z,b2.w, b3.x,b3.y,b3.z,b3.w};
    float Cv[16] = {c0.x,c0.y,c0.z,c0.w, c1.x,c1.y,c1.z,c1.w,
                    c2.x,c2.y,c2.z,c2.w, c3.x,c3.y,c3.z,c3.w};
    float yp = 0.f;
    #pragma unroll
    for (int n=0;n<16;n++){
      float a = __expf(dte*An[n]);
      h[n] = h[n]*a + dtx*Bv[n];
      yp += h[n]*Cv[n];
    }
    yrow[(size_t)l*192] = (yp + x*Dv)*siluf_(z);
  }
}

// ============ K15: instance-norm stats of `out` ============
__global__ void k_stats2(const float* __restrict__ outb, float* __restrict__ st) {
  int bc = blockIdx.x; int t = threadIdx.x;
  const float* p = outb + (size_t)bc*NSPA;
  float s=0.f, s2=0.f;
  for (int i=t;i<NSPA;i+=256){ float v=p[i]; s+=v; s2+=v*v; }
  __shared__ float red[4], red2[4];
  #pragma unroll
  for (int m=32;m>=1;m>>=1){ s += __shfl_xor(s,m); s2 += __shfl_xor(s2,m); }
  if ((t&63)==0){ red[t>>6]=s; red2[t>>6]=s2; }
  __syncthreads();
  if (t==0){
    float S=red[0]+red[1]+red[2]+red[3];
    float S2=red2[0]+red2[1]+red2[2]+red2[3];
    float mn=S/(float)NSPA; float var=S2/(float)NSPA-mn*mn;
    st[ST_MEAN2+bc]=mn; st[ST_RSTD2+bc]=rsqrtf(var+EPS);
  }
}

// ============ K16: fused xo-norm * y_sppe -> fc1 -> gelu -> fc2 -> +x ============
__global__ void k_mlp(const float* __restrict__ outb, const float* __restrict__ ysppe,
                      const float* __restrict__ x, const float* __restrict__ st,
                      const float* __restrict__ W1, const float* __restrict__ b1,
                      const float* __restrict__ W2, const float* __restrict__ b2,
                      float* __restrict__ dout) {
  __shared__ float xoS[96*32];
  __shared__ float hid[384*32];
  int b = blockIdx.y; int l0 = blockIdx.x*32; int tid = threadIdx.x;
  for (int i=tid;i<96*32;i+=256){
    int k=i>>5, l=i&31;
    size_t off = ((size_t)b*96+k)*NSPA + l0+l;
    xoS[i] = (outb[off]-st[ST_MEAN2+b*96+k])*st[ST_RSTD2+b*96+k]*ysppe[off];
  }
  __syncthreads();
  int l4=(tid&7)*4; int og=tid>>3; // og in [0,32)
  for (int o0=og*4; o0<384; o0+=128){
    float acc[16];
    #pragma unroll
    for (int i=0;i<16;i++) acc[i]=0.f;
    for (int k=0;k<96;k++){
      float4 a = *(const float4*)&xoS[k*32+l4];
      #pragma unroll
      for (int j=0;j<4;j++){
        float wv = W1[(size_t)(o0+j)*96+k];
        acc[j*4+0]+=wv*a.x; acc[j*4+1]+=wv*a.y; acc[j*4+2]+=wv*a.z; acc[j*4+3]+=wv*a.w;
      }
    }
    #pragma unroll
    for (int j=0;j<4;j++){
      int o=o0+j; float bias=b1[o];
      hid[o*32+l4+0]=geluf_(acc[j*4+0]+bias);
      hid[o*32+l4+1]=geluf_(acc[j*4+1]+bias);
      hid[o*32+l4+2]=geluf_(acc[j*4+2]+bias);
      hid[o*32+l4+3]=geluf_(acc[j*4+3]+bias);
    }
  }
  __syncthreads();
  for (int o0=og*4; o0<96; o0+=128){ // og<24 active
    float acc[16];
    #pragma unroll
    for (int i=0;i<16;i++) acc[i]=0.f;
    for (int k=0;k<384;k++){
      float4 a = *(const float4*)&hid[k*32+l4];
      #pragma unroll
      for (int j=0;j<4;j++){
        float wv = W2[(size_t)(o0+j)*384+k];
        acc[j*4+0]+=wv*a.x; acc[j*4+1]+=wv*a.y; acc[j*4+2]+=wv*a.z; acc[j*4+3]+=wv*a.w;
      }
    }
    #pragma unroll
    for (int j=0;j<4;j++){
      int o=o0+j;
      size_t off = ((size_t)b*96+o)*NSPA + l0+l4;
      float4 xin = *(const float4*)&x[off];
      float4 r;
      r.x=acc[j*4+0]+b2[o]+xin.x; r.y=acc[j*4+1]+b2[o]+xin.y;
      r.z=acc[j*4+2]+b2[o]+xin.z; r.w=acc[j*4+3]+b2[o]+xin.w;
      *(float4*)&dout[off] = r;
    }
  }
}

extern "C" void kernel_launch(void* const* d_in, const int* in_sizes, int n_in,
                              void* d_out, int out_size, void* d_ws, size_t ws_size,
                              hipStream_t stream) {
  const float* x        = (const float*)d_in[0];
  const float* c1w      = (const float*)d_in[1];
  const float* c1b      = (const float*)d_in[2];
  const float* c3w      = (const float*)d_in[3];
  const float* c3b      = (const float*)d_in[4];
  const float* gnw      = (const float*)d_in[5];
  const float* gnb      = (const float*)d_in[6];
  const float* in_proj  = (const float*)d_in[7];
  const float* conv1dw  = (const float*)d_in[8];
  const float* conv1db  = (const float*)d_in[9];
  const float* xprojw   = (const float*)d_in[10];
  const float* dtw      = (const float*)d_in[11];
  const float* dtb      = (const float*)d_in[12];
  const float* A_log    = (const float*)d_in[13];
  const float* ssm_D    = (const float*)d_in[14];
  const float* outprojw = (const float*)d_in[15];
  const float* W1       = (const float*)d_in[16];
  const float* b1       = (const float*)d_in[17];
  const float* W2       = (const float*)d_in[18];
  const float* b2       = (const float*)d_in[19];
  float* dout = (float*)d_out;

  float* ws = (float*)d_ws;
  // ---- arena; peak = 56,688,640 floats = 216.25 MiB (same as passing R2) ----
  // R_A: xm_t -> Hs                  (12.58M)
  // R_B: zg_t                        (12.58M)
  // R_C: xc_t -> y_t (in-place)      (12.58M)
  // R_D: gated -> dbl_t + P + hend   (6.29M; 2.62+1.57+1.57=5.77 used)
  // R_E: x2 -> outb                  (6.29M)
  // R_F: ysppe                       (6.29M)
  const size_t o_st = 0;
  const size_t o_A  = 65536;
  const size_t o_B  = o_A + 12582912;
  const size_t o_C  = o_B + 12582912;
  const size_t o_D  = o_C + 12582912;
  const size_t o_E  = o_D + 6291456;
  const size_t o_F  = o_E + 6291456;
  float* st    = ws + o_st;
  float* xm_t  = ws + o_A;
  float* Hs    = ws + o_A;        // xm_t dead after conv1d
  float* zg_t  = ws + o_B;
  float* xc_t  = ws + o_C;
  float* y_t   = ws + o_C;        // scanC writes y in-place over xc_t
  float* gated = ws + o_D;
  float* dbl_t = ws + o_D;        // gated dead after sppe_out
  float* P     = ws + o_D + 2621440;
  float* hend  = ws + o_D + 2621440 + 1572864;
  float* x2b   = ws + o_E;
  float* outb  = ws + o_E;        // x2 dead after sppe_out
  float* ysppe = ws + o_F;

  hipMemsetAsync(st, 0, 65536*sizeof(float), stream);

  // --- SPPE branch + inorm stats ---
  k_stats<<<192, 1024, 0, stream>>>(x, st);
  k_gates<<<16, 128, 0, stream>>>(c1w, c1b, st);
  k_gated<<<192, 1024, 0, stream>>>(x, gated, st);
  k_conv3<<<dim3(128,16), 256, 0, stream>>>(x, c3w, c3b, x2b, st);
  k_sppe_out<<<dim3(128,16), 256, 0, stream>>>(x, gated, x2b, gnw, gnb, st, ysppe);
  // --- in_proj (fused inorm), token-major outputs ---
  k_gemm_in<<<dim3(512,2), 256, 0, stream>>>(x, in_proj, xm_t, zg_t,
                                             st+ST_MEAN, st+ST_RSTD);
  // --- causal depthwise conv1d + silu (token-major) ---
  k_conv1d_t<<<dim3(256,2), 192, 0, stream>>>(xm_t, conv1dw, conv1db, xc_t);
  // --- x_proj -> dbl_t token-major [B|C|dt] ---
  k_gemm_xp<<<dim3(512,2), 256, 0, stream>>>(xc_t, xprojw, dbl_t);
  // --- chunked selective scan (dt_proj fused) ---
  k_scanA<<<dim3(NCH,2), 192, 0, stream>>>(xc_t, dbl_t, dtw, dtb, A_log, P, hend);
  k_scanB<<<24, 256, 0, stream>>>(P, hend, Hs);
  k_scanC<<<dim3(NCH,2), 192, 0, stream>>>(xc_t, dbl_t, dtw, dtb, A_log, Hs,
                                           ssm_D, zg_t, y_t);
  // --- out_proj: token-major A -> e-major outb ---
  k_gemm_out<<<dim3(512,2), 256, 0, stream>>>(y_t, outprojw, outb);
  // --- inorm stats of out + fused MLP ---
  k_stats2<<<192, 256, 0, stream>>>(outb, st);
  k_mlp<<<dim3(1024,2), 256, 0, stream>>>(outb, ysppe, x, st, W1, b1, W2, b2, dout);
}